// Round 5
// baseline (22085.173 us; speedup 1.0000x reference)
//
#include <hip/hip_runtime.h>

#define BLOCK 1024
#define GRID  256          // = #CUs: 1 block/CU (128 KB LDS forces it), co-resident
#define PPT   2            // GRID*BLOCK*PPT = 524288 >= N
#define V     8            // DIMS/4 float4s per row
#define DIMS  32
#define SLOTS_PER_THREAD (GRID / 64)   // wave-0 gather: 4 slots per lane

// Monotone map: smaller float -> smaller u32 key (ties broken by index).
__device__ __forceinline__ unsigned pack_f32(float v) {
    unsigned u = __float_as_uint(v);
    return (u & 0x80000000u) ? ~u : (u | 0x80000000u);
}

__device__ __forceinline__ unsigned long long pack_min(float v, unsigned idx) {
    return ((unsigned long long)pack_f32(v) << 32) | (unsigned long long)idx;
}

__device__ __forceinline__ unsigned long long shfl_down_u64(unsigned long long v, int off) {
    unsigned lo = (unsigned)(v & 0xffffffffu);
    unsigned hi = (unsigned)(v >> 32);
    lo = __shfl_down(lo, off, 64);
    hi = __shfl_down(hi, off, 64);
    return ((unsigned long long)hi << 32) | (unsigned long long)lo;
}

// Full-block min reduction; every thread returns the block-wide min.
__device__ __forceinline__ unsigned long long block_min_reduce(unsigned long long v,
                                                              unsigned long long* scratch) {
    #pragma unroll
    for (int off = 32; off >= 1; off >>= 1) {
        unsigned long long o = shfl_down_u64(v, off);
        v = (o < v) ? o : v;
    }
    const int wave = threadIdx.x >> 6;
    const int lane = threadIdx.x & 63;
    if (lane == 0) scratch[wave] = v;
    __syncthreads();
    unsigned long long r = scratch[0];
    #pragma unroll
    for (int i = 1; i < (BLOCK / 64); ++i) {
        unsigned long long o = scratch[i];
        r = (o < r) ? o : r;
    }
    __syncthreads();  // scratch safe for reuse
    return r;
}

// Post this block's min for step t. Slot key: [val:32 | step:12 | idx:20].
__device__ __forceinline__ void post_slot(unsigned long long* __restrict__ slots,
                                          unsigned long long blockmin, int t) {
    if (threadIdx.x == 0) {
        const unsigned long long val = blockmin >> 32;
        const unsigned long long idx = blockmin & 0xFFFFFull;   // all idx < 2^20
        const unsigned long long key =
            (val << 32) | ((unsigned long long)((unsigned)t & 0xFFFu) << 20) | idx;
        __hip_atomic_store(&slots[(size_t)(t & 1) * GRID + blockIdx.x], key,
                           __ATOMIC_RELAXED, __HIP_MEMORY_SCOPE_AGENT);
    }
}

// Wave 0 polls all GRID slots for step t; other waves wait at the barrier with
// zero memory traffic. Returns grid-wide min to ALL threads.
__device__ __forceinline__ unsigned long long gather_min(
    const unsigned long long* __restrict__ slotp, int t, unsigned long long* gmin_sh) {
    if (threadIdx.x < 64) {
        const unsigned want = (unsigned)t & 0xFFFu;
        unsigned long long k[SLOTS_PER_THREAD];
        for (;;) {
            #pragma unroll
            for (int s = 0; s < SLOTS_PER_THREAD; ++s)
                k[s] = __hip_atomic_load(&slotp[threadIdx.x + 64 * s],
                                         __ATOMIC_RELAXED, __HIP_MEMORY_SCOPE_AGENT);
            bool ok = true;
            #pragma unroll
            for (int s = 0; s < SLOTS_PER_THREAD; ++s)
                ok &= (((unsigned)(k[s] >> 20) & 0xFFFu) == want);
            if (ok) break;
        }
        unsigned long long lb = k[0];
        #pragma unroll
        for (int s = 1; s < SLOTS_PER_THREAD; ++s)
            if (k[s] < lb) lb = k[s];
        #pragma unroll
        for (int off = 32; off >= 1; off >>= 1) {
            unsigned long long o = shfl_down_u64(lb, off);
            lb = (o < lb) ? o : lb;
        }
        if (threadIdx.x == 0) *gmin_sh = lb;
    }
    __syncthreads();
    unsigned long long r = *gmin_sh;
    __syncthreads();
    return r;
}

__global__ __launch_bounds__(BLOCK, 4) void stein_thin_persist(
    const float* __restrict__ x, const float* __restrict__ log_p,
    const float* __restrict__ score_p, const float* __restrict__ laplace,
    const float* __restrict__ ls_ptr, int* __restrict__ out,
    unsigned long long* __restrict__ slots, int N, int m)
{
    const int tid = blockIdx.x * BLOCK + threadIdx.x;
    const int T = GRID * BLOCK;          // 262144

    const float ell = ls_ptr[0];
    const float ell2 = ell * ell;
    const float w = 1.0f / (float)m;                 // weight_entropy = 1/m
    const float dim_over_ell2 = (float)DIMS / ell2;

    const float4* __restrict__ X4 = (const float4*)x;
    const float4* __restrict__ S4 = (const float4*)score_p;

    // Transposed S tier for point 0: s_ldsT[v][t] = S4[row(0,t)*V + v].
    // Lane reads its own 16B chunk -> conflict-free b128 (verified round 4).
    __shared__ float4 s_ldsT[V][BLOCK];              // 128 KB
    __shared__ float4 xi4[V];
    __shared__ float4 si4[V];
    __shared__ unsigned long long gmin_sh;
    __shared__ unsigned long long red_scratch[BLOCK / 64];

    // -------- persistent per-thread state ------------------------------------
    float4 xr[PPT][V];                 // 64 VGPRs: this thread's 2 x-rows
    const float4* sptr1;               // base pointer into S for point 1 (streamed)
    float objr[PPT], lpr[PPT];

    {
        unsigned long long lbest = ~0ULL;
        #pragma unroll
        for (int p = 0; p < PPT; ++p) {
            const int j = tid + p * T;
            const bool act = (j < N);
            const int jc = act ? j : (N - 1);        // clamp: loads stay in-bounds
            const size_t base = (size_t)jc * V;
            if (p == 1) sptr1 = S4 + base;
            float ss = 0.0f;
            #pragma unroll
            for (int v = 0; v < V; ++v) {
                const float4 s = S4[base + v];
                if (p == 0) s_ldsT[v][threadIdx.x] = s;
                xr[p][v] = X4[base + v];
                ss += s.x * s.x; ss += s.y * s.y; ss += s.z * s.z; ss += s.w * s.w;
            }
            lpr[p] = log_p[jc];
            // identical source shape to the verified round-1/3/4 kernels:
            float o = ((dim_over_ell2 + ss) + laplace[jc]) - w * log_p[jc];
            if (!act) o = __int_as_float(0x7F800000);   // +inf: never selected
            objr[p] = o;
            const unsigned long long pk = pack_min(o, (unsigned)j);
            if (pk < lbest) lbest = pk;
        }
        post_slot(slots, block_min_reduce(lbest, red_scratch), 0);
    }
    __syncthreads();   // s_ldsT fully populated before the step loop

    // -------- steps 1..m-1: prefetch -> gather -> pivot -> update -> post -----
    for (int t = 1; t < m; ++t) {
        // Prefetch point-1's S row NOW (address pivot-independent, values
        // constant across steps) so the L2 round-trip overlaps the gather spin
        // and pivot staging.
        float4 sv1[V];
        #pragma unroll
        for (int v = 0; v < V; ++v) sv1[v] = sptr1[v];

        const unsigned long long gmin =
            gather_min(slots + (size_t)((t - 1) & 1) * GRID, t - 1, &gmin_sh);
        const int idx = (int)(gmin & 0xFFFFFull);
        if (blockIdx.x == 0 && threadIdx.x == 0) out[t - 1] = idx;

        // stage pivot row (x[idx], s[idx]) into LDS (L2-hit global read)
        if (threadIdx.x < 16) {
            const size_t pb = (size_t)idx * V;
            if (threadIdx.x < 8) xi4[threadIdx.x] = X4[pb + threadIdx.x];
            else                 si4[threadIdx.x - 8] = S4[pb + (threadIdx.x - 8)];
        }
        __syncthreads();

        unsigned long long lbest = ~0ULL;
        #pragma unroll
        for (int p = 0; p < PPT; ++p) {
            float r2 = 0.0f, c1 = 0.0f, c2 = 0.0f, dss = 0.0f;
            #pragma unroll
            for (int v = 0; v < V; ++v) {
                const float4 xp = xi4[v];
                const float4 sp = si4[v];
                const float4 xv = xr[p][v];
                const float4 sv = (p == 0) ? s_ldsT[v][threadIdx.x] : sv1[v];
                float d;
                d = xp.x - xv.x; r2 += d * d; c1 += d * sp.x; c2 += sv.x * d; dss += sv.x * sp.x;
                d = xp.y - xv.y; r2 += d * d; c1 += d * sp.y; c2 += sv.y * d; dss += sv.y * sp.y;
                d = xp.z - xv.z; r2 += d * d; c1 += d * sp.z; c2 += sv.z * d; dss += sv.z * sp.z;
                d = xp.w - xv.w; r2 += d * d; c1 += d * sp.w; c2 += sv.w * d; dss += sv.w * sp.w;
            }
            const float q   = 1.0f + r2 / ell2;
            const float qi  = 1.0f / q;
            const float sq  = sqrtf(qi);        // q^-0.5
            const float g   = qi * sq;          // q^-1.5
            const float q25 = qi * qi * sq;     // q^-2.5
            const float cross = (c1 - c2) / ell2;
            const float k = ((dim_over_ell2 * g - 3.0f * r2 / (ell2 * ell2) * q25)
                             + cross * g) + dss * sq;
            // +inf rows stay +inf (their loads were clamped to a real row => k finite)
            const float o = objr[p] + (2.0f * k - w * lpr[p]);
            objr[p] = o;
            const unsigned long long pk = pack_min(o, (unsigned)(tid + p * T));
            if (pk < lbest) lbest = pk;
        }
        post_slot(slots, block_min_reduce(lbest, red_scratch), t);
    }

    // -------- final argmin -> out[m-1] ----------------------------------------
    {
        const unsigned long long gmin =
            gather_min(slots + (size_t)((m - 1) & 1) * GRID, m - 1, &gmin_sh);
        if (blockIdx.x == 0 && threadIdx.x == 0) out[m - 1] = (int)(gmin & 0xFFFFFull);
    }
}

extern "C" void kernel_launch(void* const* d_in, const int* in_sizes, int n_in,
                              void* d_out, int out_size, void* d_ws, size_t ws_size,
                              hipStream_t stream) {
    const float* x        = (const float*)d_in[0];
    const float* log_p    = (const float*)d_in[1];
    const float* score_p  = (const float*)d_in[2];
    const float* laplace  = (const float*)d_in[3];
    const float* ls_ptr   = (const float*)d_in[4];

    int* out = (int*)d_out;
    int N = in_sizes[1];            // log_p has N elements
    int m = out_size;

    unsigned long long* slots = (unsigned long long*)d_ws;  // 2*GRID u64 = 4 KB

    void* args[] = {(void*)&x, (void*)&log_p, (void*)&score_p, (void*)&laplace,
                    (void*)&ls_ptr, (void*)&out, (void*)&slots, (void*)&N, (void*)&m};

    hipError_t err = hipLaunchCooperativeKernel((void*)stein_thin_persist,
                                                dim3(GRID), dim3(BLOCK), args, 0, stream);
    if (err != hipSuccess) {
        (void)hipGetLastError();
        // 128 KB LDS forces 1 block/CU; grid == #CUs keeps a plain launch
        // fully co-resident as well.
        stein_thin_persist<<<dim3(GRID), dim3(BLOCK), 0, stream>>>(
            x, log_p, score_p, laplace, ls_ptr, out, slots, N, m);
    }
}

// Round 8
// 16860.970 us; speedup vs baseline: 1.3098x; 1.3098x over previous
//
#include <hip/hip_runtime.h>

#define BLOCK 512
#define GRID  256          // = #CUs; 155KB LDS => 1 block/CU => plain launch co-resident
#define PPT   4            // GRID*BLOCK*PPT = 524288 >= N
#define V     8            // DIMS/4 float4s per row
#define V3    3            // float4s of point 3 parked in LDS (rest streamed)
#define DIMS  32
#define SLOTS_PER_THREAD (GRID / 64)   // wave-0 gather: 4 slots per lane

// Monotone map: smaller float -> smaller u32 key (ties broken by index).
__device__ __forceinline__ unsigned pack_f32(float v) {
    unsigned u = __float_as_uint(v);
    return (u & 0x80000000u) ? ~u : (u | 0x80000000u);
}

__device__ __forceinline__ unsigned long long pack_min(float v, unsigned idx) {
    return ((unsigned long long)pack_f32(v) << 32) | (unsigned long long)idx;
}

__device__ __forceinline__ unsigned long long shfl_down_u64(unsigned long long v, int off) {
    unsigned lo = (unsigned)(v & 0xffffffffu);
    unsigned hi = (unsigned)(v >> 32);
    lo = __shfl_down(lo, off, 64);
    hi = __shfl_down(hi, off, 64);
    return ((unsigned long long)hi << 32) | (unsigned long long)lo;
}

// Full-block min reduction; every thread returns the block-wide min.
__device__ __forceinline__ unsigned long long block_min_reduce(unsigned long long v,
                                                              unsigned long long* scratch) {
    #pragma unroll
    for (int off = 32; off >= 1; off >>= 1) {
        unsigned long long o = shfl_down_u64(v, off);
        v = (o < v) ? o : v;
    }
    const int wave = threadIdx.x >> 6;
    const int lane = threadIdx.x & 63;
    if (lane == 0) scratch[wave] = v;
    __syncthreads();
    unsigned long long r = scratch[0];
    #pragma unroll
    for (int i = 1; i < (BLOCK / 64); ++i) {
        unsigned long long o = scratch[i];
        r = (o < r) ? o : r;
    }
    __syncthreads();  // scratch safe for reuse
    return r;
}

// Post this block's min for step t. Slot key: [val:32 | step:12 | idx:20].
__device__ __forceinline__ void post_slot(unsigned long long* __restrict__ slots,
                                          unsigned long long blockmin, int t) {
    if (threadIdx.x == 0) {
        const unsigned long long val = blockmin >> 32;
        const unsigned long long idx = blockmin & 0xFFFFFull;   // all idx < 2^20
        const unsigned long long key =
            (val << 32) | ((unsigned long long)((unsigned)t & 0xFFFu) << 20) | idx;
        __hip_atomic_store(&slots[(size_t)(t & 1) * GRID + blockIdx.x], key,
                           __ATOMIC_RELAXED, __HIP_MEMORY_SCOPE_AGENT);
    }
}

// Wave 0 polls all GRID slots for step t; other waves wait at the barrier with
// zero memory traffic. Returns grid-wide min to ALL threads.
// Safety of the 2-buffer reuse: a block posts t+2 (same parity as t) only after
// gathering all t+1 posts, each of which required its author to finish reading
// every step-t slot — so no step-t slot is overwritten before all reads.
__device__ __forceinline__ unsigned long long gather_min(
    const unsigned long long* __restrict__ slotp, int t, unsigned long long* gmin_sh) {
    if (threadIdx.x < 64) {
        const unsigned want = (unsigned)t & 0xFFFu;
        unsigned long long k[SLOTS_PER_THREAD];
        for (;;) {
            #pragma unroll
            for (int s = 0; s < SLOTS_PER_THREAD; ++s)
                k[s] = __hip_atomic_load(&slotp[threadIdx.x + 64 * s],
                                         __ATOMIC_RELAXED, __HIP_MEMORY_SCOPE_AGENT);
            bool ok = true;
            #pragma unroll
            for (int s = 0; s < SLOTS_PER_THREAD; ++s)
                ok &= (((unsigned)(k[s] >> 20) & 0xFFFu) == want);
            if (ok) break;
        }
        unsigned long long lb = k[0];
        #pragma unroll
        for (int s = 1; s < SLOTS_PER_THREAD; ++s)
            if (k[s] < lb) lb = k[s];
        #pragma unroll
        for (int off = 32; off >= 1; off >>= 1) {
            unsigned long long o = shfl_down_u64(lb, off);
            lb = (o < lb) ? o : lb;
        }
        if (threadIdx.x == 0) *gmin_sh = lb;
    }
    __syncthreads();
    unsigned long long r = *gmin_sh;
    __syncthreads();
    return r;
}

__global__ __launch_bounds__(BLOCK) void stein_thin_persist(
    const float* __restrict__ x, const float* __restrict__ log_p,
    const float* __restrict__ score_p, const float* __restrict__ laplace,
    const float* __restrict__ ls_ptr, int* __restrict__ out,
    unsigned long long* __restrict__ slots, int N, int m)
{
    const int tid = blockIdx.x * BLOCK + threadIdx.x;
    const int T = GRID * BLOCK;          // 131072

    const float ell = ls_ptr[0];
    const float ell2 = ell * ell;
    const float w = 1.0f / (float)m;                 // weight_entropy = 1/m
    const float dim_over_ell2 = (float)DIMS / ell2;

    const float4* __restrict__ X4 = (const float4*)x;
    const float4* __restrict__ S4 = (const float4*)score_p;

    // LDS budget (160 KB/CU): tier A 128 KB + tier B 24 KB + pivot/reduce ~0.5 KB.
    // Transposed layout: lane reads its own 16B chunk -> conflict-free b128
    // (verified rounds 4/5: SQ_LDS_BANK_CONFLICT = 0).
    __shared__ float4 s_ldsT[V][2 * BLOCK];   // S-rows of points 0,1 (128 KB)
    __shared__ float4 s_lds3[V3][BLOCK];      // first 3 float4s of point 3 (24 KB)
    __shared__ float4 xi4[V];
    __shared__ float4 si4[V];
    __shared__ unsigned long long gmin_sh;
    __shared__ unsigned long long red_scratch[BLOCK / 64];

    // -------- persistent per-thread state ------------------------------------
    float4 xr[PPT][V];                 // 128 VGPRs: this thread's 4 x-rows
    const float4* sptr2;               // streamed S base, point 2
    const float4* sptr3;               // streamed S base, point 3 (v >= V3)
    float objr[PPT], lpr[PPT];

    {
        unsigned long long lbest = ~0ULL;
        #pragma unroll
        for (int p = 0; p < PPT; ++p) {
            const int j = tid + p * T;
            const bool act = (j < N);
            const int jc = act ? j : (N - 1);        // clamp: loads stay in-bounds
            const size_t base = (size_t)jc * V;
            if (p == 2) sptr2 = S4 + base;
            if (p == 3) sptr3 = S4 + base;
            float ss = 0.0f;
            #pragma unroll
            for (int v = 0; v < V; ++v) {
                const float4 s = S4[base + v];
                if (p < 2) s_ldsT[v][p * BLOCK + threadIdx.x] = s;
                if (p == 3 && v < V3) s_lds3[v][threadIdx.x] = s;
                xr[p][v] = X4[base + v];
                ss += s.x * s.x; ss += s.y * s.y; ss += s.z * s.z; ss += s.w * s.w;
            }
            lpr[p] = log_p[jc];
            // identical source shape to the verified round-1/3/4/5 kernels:
            float o = ((dim_over_ell2 + ss) + laplace[jc]) - w * log_p[jc];
            if (!act) o = __int_as_float(0x7F800000);   // +inf: never selected
            objr[p] = o;
            const unsigned long long pk = pack_min(o, (unsigned)j);
            if (pk < lbest) lbest = pk;
        }
        post_slot(slots, block_min_reduce(lbest, red_scratch), 0);
    }
    __syncthreads();   // LDS tiers fully populated before the step loop

    // -------- steps 1..m-1: gather -> pivot -> update -> post -----------------
    for (int t = 1; t < m; ++t) {
        const unsigned long long gmin =
            gather_min(slots + (size_t)((t - 1) & 1) * GRID, t - 1, &gmin_sh);
        const int idx = (int)(gmin & 0xFFFFFull);
        if (blockIdx.x == 0 && threadIdx.x == 0) out[t - 1] = idx;

        // stage pivot row (x[idx], s[idx]) into LDS
        if (threadIdx.x < 16) {
            const size_t pb = (size_t)idx * V;
            if (threadIdx.x < 8) xi4[threadIdx.x] = X4[pb + threadIdx.x];
            else                 si4[threadIdx.x - 8] = S4[pb + (threadIdx.x - 8)];
        }
        __syncthreads();

        unsigned long long lbest = ~0ULL;
        #pragma unroll
        for (int p = 0; p < PPT; ++p) {
            float r2 = 0.0f, c1 = 0.0f, c2 = 0.0f, dss = 0.0f;
            #pragma unroll
            for (int v = 0; v < V; ++v) {
                const float4 xp = xi4[v];
                const float4 sp = si4[v];
                const float4 xv = xr[p][v];
                const float4 sv = (p < 2)  ? s_ldsT[v][p * BLOCK + threadIdx.x]
                                 : (p == 2) ? sptr2[v]
                                 : (v < V3) ? s_lds3[v][threadIdx.x]
                                            : sptr3[v];
                float d;
                d = xp.x - xv.x; r2 += d * d; c1 += d * sp.x; c2 += sv.x * d; dss += sv.x * sp.x;
                d = xp.y - xv.y; r2 += d * d; c1 += d * sp.y; c2 += sv.y * d; dss += sv.y * sp.y;
                d = xp.z - xv.z; r2 += d * d; c1 += d * sp.z; c2 += sv.z * d; dss += sv.z * sp.z;
                d = xp.w - xv.w; r2 += d * d; c1 += d * sp.w; c2 += sv.w * d; dss += sv.w * sp.w;
            }
            const float q   = 1.0f + r2 / ell2;
            const float qi  = 1.0f / q;
            const float sq  = sqrtf(qi);        // q^-0.5
            const float g   = qi * sq;          // q^-1.5
            const float q25 = qi * qi * sq;     // q^-2.5
            const float cross = (c1 - c2) / ell2;
            const float k = ((dim_over_ell2 * g - 3.0f * r2 / (ell2 * ell2) * q25)
                             + cross * g) + dss * sq;
            // +inf rows stay +inf (their loads were clamped to a real row => k finite)
            const float o = objr[p] + (2.0f * k - w * lpr[p]);
            objr[p] = o;
            const unsigned long long pk = pack_min(o, (unsigned)(tid + p * T));
            if (pk < lbest) lbest = pk;
        }
        post_slot(slots, block_min_reduce(lbest, red_scratch), t);
    }

    // -------- final argmin -> out[m-1] ----------------------------------------
    {
        const unsigned long long gmin =
            gather_min(slots + (size_t)((m - 1) & 1) * GRID, m - 1, &gmin_sh);
        if (blockIdx.x == 0 && threadIdx.x == 0) out[m - 1] = (int)(gmin & 0xFFFFFull);
    }
}

extern "C" void kernel_launch(void* const* d_in, const int* in_sizes, int n_in,
                              void* d_out, int out_size, void* d_ws, size_t ws_size,
                              hipStream_t stream) {
    const float* x        = (const float*)d_in[0];
    const float* log_p    = (const float*)d_in[1];
    const float* score_p  = (const float*)d_in[2];
    const float* laplace  = (const float*)d_in[3];
    const float* ls_ptr   = (const float*)d_in[4];

    int* out = (int*)d_out;
    int N = in_sizes[1];            // log_p has N elements
    int m = out_size;

    unsigned long long* slots = (unsigned long long*)d_ws;  // 2*GRID u64 = 4 KB

    // Single deterministic path: plain launch, identical on every call
    // (correctness call, graph capture, tripwire). 155 KB LDS => exactly
    // 1 block/CU => 256 blocks on 256 CUs are structurally co-resident.
    stein_thin_persist<<<dim3(GRID), dim3(BLOCK), 0, stream>>>(
        x, log_p, score_p, laplace, ls_ptr, out, slots, N, m);
}